// Round 10
// baseline (94.013 us; speedup 1.0000x reference)
//
#include <hip/hip_runtime.h>

#define NB      2000
#define NT      365
#define LENF    15
#define PSTRIDE 96              // 12 params * 8 muls, floats per (b,t)
#define CH      16              // timesteps per chunk
#define NFULL   22              // full chunks (352 steps)
#define NCHUNK  23              // incl. 13-step tail
#define CHBYTES (CH * PSTRIDE * 4)              // 6144 B per chunk per basin
#define BASIN_BYTES (NT * PSTRIDE * 4)          // 140160
#define CLAMP16     (BASIN_BYTES - 16)          // 140144
#define PARW    1544            // LDS words per basin param block (1536 + 8 pad; 1544%32==8)
#define FRCW    72              // LDS words per basin forcing block (64 + pad; 72%32==8)
#define NBW     4               // basins per wave
// VMEM ops per ISSUE = 24 GLD16 + 4 GLD4 = 28 -> main-loop wait is vmcnt(28)

#define GLD16(g, l) __builtin_amdgcn_global_load_lds( \
    (const __attribute__((address_space(1))) void*)(g), \
    (__attribute__((address_space(3))) void*)(l), 16, 0, 0)
#define GLD4(g, l) __builtin_amdgcn_global_load_lds( \
    (const __attribute__((address_space(1))) void*)(g), \
    (__attribute__((address_space(3))) void*)(l), 4, 0, 0)

#define EXP2F(x) __builtin_amdgcn_exp2f(x)
#define LOG2F(x) __builtin_amdgcn_logf(x)
#define LOG2E    1.44269504088896f

// DPP cross-lane ops — pure VALU, no LDS pipe, no lgkmcnt.
template <int CTRL>
__device__ __forceinline__ float dpp_mov(float x) {
  int xi = __float_as_int(x);
  int r  = __builtin_amdgcn_update_dpp(xi, xi, CTRL, 0xF, 0xF, true);
  return __int_as_float(r);
}
#define DPP_XOR1   0xB1    // quad_perm [1,0,3,2]
#define DPP_XOR2   0x4E    // quad_perm [2,3,0,1]
#define DPP_HMIRR  0x141   // row_half_mirror: i <-> 7-i within each 8-lane half

// FOUR BASINS PER WAVE (lane = dup*32 + bsel*8 + m), 500 blocks -> ~2 waves/CU.
// R8 lesson: 48-read batches exceed lgkmcnt's 4-bit range (max 15), forcing
// over-conservative waits that serialize the batch pipeline. This version:
// (a) B=4 halves per-CU DS issue (chip DS instrs = (2000/B)*365*12);
// (b) 1-step ping-pong register pipeline, 12 reads/step <= 15, so the
// compiler's fine-grained lgkmcnt(12) lets load(s+1) hide under STEP(s).
__global__ __launch_bounds__(64) void prms_kernel(
    const float* __restrict__ P, const float* __restrict__ Ep,
    const float* __restrict__ Tair, const float* __restrict__ params,
    const float* __restrict__ rout_a, const float* __restrict__ rout_b,
    float* __restrict__ out)
{
  __shared__ __attribute__((aligned(16))) float sh_par[2][NBW * PARW];  // 49408 B
  __shared__ __attribute__((aligned(16))) float sh_frc[2][NBW][FRCW];   //  2304 B
  __shared__ float Qs[NBW][NT + 3];                                     //  5888 B

  const int lane = threadIdx.x;        // 0..63
  const int m    = lane & 7;           // mul index
  const int bsel = (lane >> 3) & 3;    // which of the wave's 4 basins
  const int b0   = blockIdx.x * NBW;   // first basin of this block

  // preload routing params early — latency hidden under the scan
  float ra[NBW], rb[NBW];
  #pragma unroll
  for (int bs = 0; bs < NBW; ++bs) { ra[bs] = rout_a[b0 + bs]; rb[bs] = rout_b[b0 + bs]; }

  const char* pbg[NBW];
  #pragma unroll
  for (int bs = 0; bs < NBW; ++bs)
    pbg[bs] = (const char*)(params + (size_t)(b0 + bs) * (NT * PSTRIDE));

  // forcing source for the GLD4s: lane -> (arr = lane>>4 clamped to 2, s = lane&15)
  const int farr = (lane >> 4) > 2 ? 2 : (lane >> 4);
  const int fs   = lane & 15;
  const float* fptr[NBW];
  #pragma unroll
  for (int bs = 0; bs < NBW; ++bs) {
    const float* base = (farr == 0) ? P : (farr == 1) ? Ep : Tair;
    fptr[bs] = base + (size_t)(b0 + bs) * NT;
  }

  // ---- staging: 24x GLD16 (params) + 4x GLD4 (forcings) per chunk ----
  auto ISSUE = [&](int c, int buf) {
    #pragma unroll
    for (int bs = 0; bs < NBW; ++bs) {
      #pragma unroll
      for (int j = 0; j < 6; ++j) {
        int off = c * CHBYTES + j * 1024 + lane * 16;
        off = off > CLAMP16 ? CLAMP16 : off;   // tail clamp (dups land on p=11 words, unread)
        GLD16(pbg[bs] + off, &sh_par[buf][bs * PARW + j * 256]);
      }
    }
    #pragma unroll
    for (int bs = 0; bs < NBW; ++bs) {
      int ft = c * CH + fs;
      ft = ft > NT - 1 ? NT - 1 : ft;
      GLD4(fptr[bs] + ft, &sh_frc[buf][bs][0]);
    }
  };

  float S1 = 0.5f, S2 = 0.5f, S3 = 0.5f, S4 = 0.5f, S5 = 0.5f;
  const int pbase = bsel * PARW + m;    // thread-const param word base

  // ---- per-step LDS->register load: 12 values, static indices ----
  auto LOADR = [&](int buf, int s, float* r) {
    const float* par = &sh_par[buf][pbase + s * PSTRIDE];
    r[0] = par[0];   r[1] = par[8];   r[2] = par[24];
    r[3] = par[32];  r[4] = par[40];  r[5] = par[48];
    r[6] = par[64];  r[7] = par[72];  r[8] = par[80];
    const float* f = &sh_frc[buf][bsel][0];
    r[9]  = f[s];
    r[10] = f[16 + s];
    r[11] = f[32 + s];
  };

  auto STEPD = [&](const float* d, int t) {
    const float tt    = fmaf(d[0], 8.0f, -3.0f);
    const float ddf   = d[1] * 20.0f;
    const float Smax3 = fmaf(d[2], 680.0f, 20.0f);
    const float p_lo  = fmaf(d[3], 0.99f, 0.005f);
    const float p_hi  = fmaf(d[4], 0.99f, 0.005f);
    const float p_exp = fmaf(d[5], 4.0f, 1.0f);
    const float i1    = d[6];
    const float i2    = d[7] * 0.001f;
    const float kb    = d[8];
    const float Pt    = d[9];
    const float Ept   = d[10];
    const float Tt    = d[11];

    const float snow = (Tt <= tt) ? Pt : 0.0f;
    const float rain = Pt - snow;
    const float melt = fmaxf(fminf(ddf * (Tt - tt), S1), 0.0f);   // DT=1
    S1 = S1 + snow - melt;

    const float inter = rain * 0.95f;
    const float evap2 = fminf(S2, Ept);
    S2 = fmaxf(S2 + (rain - inter) - evap2, 0.0f);

    const float infil  = melt + inter;
    const float frac   = fmaxf(S3, 0.0f) * __builtin_amdgcn_rcpf(Smax3);
    const float satexc = (p_lo + (p_hi - p_lo) * frac) * infil;
    const float rem    = fmaxf(infil - satexc, 0.0f);
    // frac^p_exp: frac==0 -> log2=-inf -> exp2(-inf)=0 (matches 0**p, p>=1)
    const float rech   = rem * EXP2F(p_exp * LOG2F(frac));
    const float evap3  = fminf(frac * Ept, S3);
    S3 = S3 + rem - rech - evap3;

    const float S4c   = fmaxf(S4, 0.0f);
    const float iflow = fminf(S4c, fmaf(i2, S4c * S4c, i1 * S4c));
    S4 = S4 + rech - iflow;

    const float base = kb * S5;
    S5 = S5 + iflow - base;

    float q = satexc + base;
    q += dpp_mov<DPP_XOR1>(q);
    q += dpp_mov<DPP_XOR2>(q);
    q += dpp_mov<DPP_HMIRR>(q);
    if ((lane & 39) == 0)                // m==0 && dup==0: lanes 0,8,16,24
      Qs[bsel][t] = q * 0.125f;
  };

  // ---- depth-2 chunk pipeline; 1-step ping-pong register pipeline inside ----
  float r[2][12];
  ISSUE(0, 0);
  ISSUE(1, 1);
  for (int c = 0; c < NFULL; ++c) {
    asm volatile("s_waitcnt vmcnt(28)" ::: "memory");   // = ops/ISSUE; chunk c resident
    const int buf = c & 1;
    const int t0  = c * CH;
    LOADR(buf, 0, r[0]);
    #pragma unroll
    for (int s = 0; s < CH; ++s) {
      if (s < CH - 1) LOADR(buf, s + 1, r[(s + 1) & 1]);
      STEPD(r[s & 1], t0 + s);
    }
    asm volatile("s_waitcnt lgkmcnt(0)" ::: "memory");  // reads of buf drained
    if (c + 2 < NCHUNK) ISSUE(c + 2, buf);
  }
  // tail chunk (c = 22): 13 valid steps, buf = 0
  asm volatile("s_waitcnt vmcnt(0)" ::: "memory");
  {
    const int t0 = NFULL * CH;           // 352
    LOADR(0, 0, r[0]);
    #pragma unroll
    for (int s = 0; s < 13; ++s) {
      if (s < 12) LOADR(0, s + 1, r[(s + 1) & 1]);
      STEPD(r[s & 1], t0 + s);
    }
  }

  __syncthreads();

  // ---- fused gamma routing conv, per basin (all 64 lanes) ----
  #pragma unroll
  for (int bs = 0; bs < NBW; ++bs) {
    const float aa  = fmaxf(ra[bs] * 2.9f, 0.0f) + 0.1f;
    const float th  = fmaxf(rb[bs] * 6.5f, 0.0f) + 0.5f;
    const float am1 = aa - 1.0f;
    const float ith = -LOG2E / th;

    float w[LENF];
    float wsum = 0.0f;
    #pragma unroll
    for (int j = 0; j < LENF; ++j) {
      const float tj = (float)j + 0.5f;
      w[j] = EXP2F(fmaf(am1, LOG2F(tj), tj * ith));
      wsum += w[j];
    }
    const float inv = 1.0f / wsum;
    #pragma unroll
    for (int j = 0; j < LENF; ++j) w[j] *= inv;

    float* __restrict__ ob = out + (size_t)(b0 + bs) * NT;
    #pragma unroll
    for (int k = 0; k < 6; ++k) {
      const int t = lane + k * 64;
      if (t < NT) {
        float acc = 0.0f;
        #pragma unroll
        for (int j = 0; j < LENF; ++j) {
          const int idx = t - j;
          if (idx >= 0) acc += w[j] * Qs[bs][idx];
        }
        ob[t] = acc;
      }
    }
  }
}

extern "C" void kernel_launch(void* const* d_in, const int* in_sizes, int n_in,
                              void* d_out, int out_size, void* d_ws, size_t ws_size,
                              hipStream_t stream) {
  const float* P      = (const float*)d_in[0];
  const float* Ep     = (const float*)d_in[1];
  const float* Tair   = (const float*)d_in[2];
  const float* params = (const float*)d_in[3];
  const float* ra     = (const float*)d_in[4];
  const float* rb     = (const float*)d_in[5];
  float* out = (float*)d_out;

  prms_kernel<<<NB / NBW, 64, 0, stream>>>(P, Ep, Tair, params, ra, rb, out);
}

// Round 11
// 92.297 us; speedup vs baseline: 1.0186x; 1.0186x over previous
//
#include <hip/hip_runtime.h>

#define NB      2000
#define NT      365
#define LENF    15
#define PSTRIDE 96              // 12 params * 8 muls, floats per (b,t)

#define EXP2F(x) __builtin_amdgcn_exp2f(x)
#define LOG2F(x) __builtin_amdgcn_logf(x)
#define LOG2E    1.44269504088896f

// DPP cross-lane ops — pure VALU, no LDS pipe, no lgkmcnt.
template <int CTRL>
__device__ __forceinline__ float dpp_mov(float x) {
  int xi = __float_as_int(x);
  int r  = __builtin_amdgcn_update_dpp(xi, xi, CTRL, 0xF, 0xF, true);
  return __int_as_float(r);
}
#define DPP_XOR1   0xB1    // quad_perm [1,0,3,2]
#define DPP_XOR2   0x4E    // quad_perm [2,3,0,1]
#define DPP_HMIRR  0x141   // row_half_mirror: i <-> 7-i within each 8-lane half

// TWO BASINS PER WAVE (lane = d*16 + bsel*8 + m), 1000 blocks -> ~4 waves/CU.
// ALL-REGISTER streaming: no LDS staging at all. Each step's 12 operands are
// loaded by plain global_load_dword into a 4-deep modulo register rotation
// (rr[4][12], static indices); compiler emits counted vmcnt (6-bit, up to 48
// outstanding) — sidesteps the LDS-pipe issue floor (~41us at B=2), the
// 4-bit lgkmcnt ceiling, and global_load_lds->ds_read alias conservatism
// that stalled R6-R10. LDS holds only the Q time series for the fused conv.
__global__ __launch_bounds__(64) void prms_kernel(
    const float* __restrict__ P, const float* __restrict__ Ep,
    const float* __restrict__ Tair, const float* __restrict__ params,
    const float* __restrict__ rout_a, const float* __restrict__ rout_b,
    float* __restrict__ out)
{
  __shared__ float Qs[2][NT + 3];     // ~2.9 KB

  const int lane = threadIdx.x;       // 0..63
  const int m    = lane & 7;          // mul index
  const int bsel = (lane >> 3) & 1;   // which of the wave's 2 basins
  const int b0   = blockIdx.x * 2;
  const int b    = b0 + bsel;

  // preload routing params early — latency hidden under the scan
  const float ra0 = rout_a[b0],     rb0 = rout_b[b0];
  const float ra1 = rout_a[b0 + 1], rb1 = rout_b[b0 + 1];

  // per-lane stream pointers
  const float* pl = params + (size_t)b * (NT * PSTRIDE) + m;  // param base (this lane's m)
  const float* fP = P    + (size_t)b * NT;
  const float* fE = Ep   + (size_t)b * NT;
  const float* fT = Tair + (size_t)b * NT;

  float S1 = 0.5f, S2 = 0.5f, S3 = 0.5f, S4 = 0.5f, S5 = 0.5f;

  // ---- register rotation: 4 steps x 12 operands, all statically indexed ----
  float rr[4][12];

  // lp: base pointer, so: step offset from lp (compile-time in every use)
  auto LOADP = [&](float* r, const float* lp, int so) {
    const float* q = lp + so * PSTRIDE;
    r[0] = q[0];   r[1] = q[8];   r[2] = q[24];
    r[3] = q[32];  r[4] = q[40];  r[5] = q[48];
    r[6] = q[64];  r[7] = q[72];  r[8] = q[80];
  };
  auto LOADF = [&](float* r, const float* p0, const float* p1, const float* p2, int o) {
    r[9]  = p0[o];
    r[10] = p1[o];
    r[11] = p2[o];
  };

  auto STEPD = [&](const float* d, int t) {
    const float tt    = fmaf(d[0], 8.0f, -3.0f);
    const float ddf   = d[1] * 20.0f;
    const float Smax3 = fmaf(d[2], 680.0f, 20.0f);
    const float p_lo  = fmaf(d[3], 0.99f, 0.005f);
    const float p_hi  = fmaf(d[4], 0.99f, 0.005f);
    const float p_exp = fmaf(d[5], 4.0f, 1.0f);
    const float i1    = d[6];
    const float i2    = d[7] * 0.001f;
    const float kb    = d[8];
    const float Pt    = d[9];
    const float Ept   = d[10];
    const float Tt    = d[11];

    const float snow = (Tt <= tt) ? Pt : 0.0f;
    const float rain = Pt - snow;
    const float melt = fmaxf(fminf(ddf * (Tt - tt), S1), 0.0f);   // DT=1
    S1 = S1 + snow - melt;

    const float inter = rain * 0.95f;
    const float evap2 = fminf(S2, Ept);
    S2 = fmaxf(S2 + (rain - inter) - evap2, 0.0f);

    const float infil  = melt + inter;
    const float frac   = fmaxf(S3, 0.0f) * __builtin_amdgcn_rcpf(Smax3);
    const float satexc = (p_lo + (p_hi - p_lo) * frac) * infil;
    const float rem    = fmaxf(infil - satexc, 0.0f);
    // frac^p_exp: frac==0 -> log2=-inf -> exp2(-inf)=0 (matches 0**p, p>=1)
    const float rech   = rem * EXP2F(p_exp * LOG2F(frac));
    const float evap3  = fminf(frac * Ept, S3);
    S3 = S3 + rem - rech - evap3;

    const float S4c   = fmaxf(S4, 0.0f);
    const float iflow = fminf(S4c, fmaf(i2, S4c * S4c, i1 * S4c));
    S4 = S4 + rech - iflow;

    const float base = kb * S5;
    S5 = S5 + iflow - base;

    float q = satexc + base;
    q += dpp_mov<DPP_XOR1>(q);
    q += dpp_mov<DPP_XOR2>(q);
    q += dpp_mov<DPP_HMIRR>(q);
    if ((lane & 55) == 0)                // m==0 && d==0: lanes 0 and 8
      Qs[bsel][t] = q * 0.125f;
  };

  // ---- prologue: load steps 0..3 (48 VMEM in flight) ----
  #pragma unroll
  for (int s = 0; s < 4; ++s) {
    LOADP(rr[s], pl, s);                 // byte offsets <= (3*96+80)*4 < 4KB
    LOADF(rr[s], fP, fE, fT, s);
  }

  // ---- main: 45 groups of 8 steps (t = 0..359); loads reach t = 363 ----
  const float* gp = pl;
  for (int g = 0; g < 45; ++g) {
    const int t0 = g * 8;
    const float* gp4 = gp + 4 * PSTRIDE;   // loads for t0+4..t0+7  (offs s*384+p*32 B)
    const float* gp8 = gp + 8 * PSTRIDE;   // loads for t0+8..t0+11
    #pragma unroll
    for (int s = 0; s < 8; ++s) {
      STEPD(rr[s & 3], t0 + s);            // uses slot, then refill same slot:
      if (s < 4) LOADP(rr[s & 3], gp4, s);
      else       LOADP(rr[s & 3], gp8, s - 4);
      LOADF(rr[s & 3], fP, fE, fT, s + 4); // byte offset <= 44
    }
    gp += 8 * PSTRIDE; fP += 8; fE += 8; fT += 8;
  }
  // ---- tail: t = 360..364 (slot = s&3 since 360 % 4 == 0) ----
  {
    const float* gp4 = gp + 4 * PSTRIDE;
    #pragma unroll
    for (int s = 0; s < 5; ++s) {
      STEPD(rr[s & 3], 360 + s);
      if (s == 0) {                        // only step 364 remains to load
        LOADP(rr[0], gp4, 0);
        LOADF(rr[0], fP, fE, fT, 4);
      }
    }
  }

  __syncthreads();

  // ---- fused gamma routing conv, per basin (all 64 lanes) ----
  #pragma unroll
  for (int bs = 0; bs < 2; ++bs) {
    const float ra_v = bs ? ra1 : ra0;
    const float rb_v = bs ? rb1 : rb0;
    const float aa  = fmaxf(ra_v * 2.9f, 0.0f) + 0.1f;
    const float th  = fmaxf(rb_v * 6.5f, 0.0f) + 0.5f;
    const float am1 = aa - 1.0f;
    const float ith = -LOG2E / th;

    float w[LENF];
    float wsum = 0.0f;
    #pragma unroll
    for (int j = 0; j < LENF; ++j) {
      const float tj = (float)j + 0.5f;
      w[j] = EXP2F(fmaf(am1, LOG2F(tj), tj * ith));
      wsum += w[j];
    }
    const float inv = 1.0f / wsum;
    #pragma unroll
    for (int j = 0; j < LENF; ++j) w[j] *= inv;

    float* __restrict__ ob = out + (size_t)(b0 + bs) * NT;
    #pragma unroll
    for (int k = 0; k < 6; ++k) {
      const int t = lane + k * 64;
      if (t < NT) {
        float acc = 0.0f;
        #pragma unroll
        for (int j = 0; j < LENF; ++j) {
          const int idx = t - j;
          if (idx >= 0) acc += w[j] * Qs[bs][idx];
        }
        ob[t] = acc;
      }
    }
  }
}

extern "C" void kernel_launch(void* const* d_in, const int* in_sizes, int n_in,
                              void* d_out, int out_size, void* d_ws, size_t ws_size,
                              hipStream_t stream) {
  const float* P      = (const float*)d_in[0];
  const float* Ep     = (const float*)d_in[1];
  const float* Tair   = (const float*)d_in[2];
  const float* params = (const float*)d_in[3];
  const float* ra     = (const float*)d_in[4];
  const float* rb     = (const float*)d_in[5];
  float* out = (float*)d_out;

  prms_kernel<<<NB / 2, 64, 0, stream>>>(P, Ep, Tair, params, ra, rb, out);
}